// Round 11
// baseline (412.353 us; speedup 1.0000x reference)
//
#include <hip/hip_runtime.h>

// ---------------------------------------------------------------------------
// GNN forward, MI355X. All I/O f32; split-f16 MFMA edge MLP (R8-verified,
// bit-identical); GRU/projections f32 VALU, bit-identical order to R10.
// R11: k_node fused into k_iter. R10 evidence: k_node+k_pre ~150us of wall
// for ~2us of FLOPs (serialized launch phases at 2 blocks/CU), while each
// k_edge block already holds the COMPLETE m_i for its 8 nodes. The GRU/
// node-update/next-iter Q,P projection are block-local; the kernel boundary
// between iterations is the only cross-block sync needed (P reads).
// Weight access in the tails uses original layouts (lane = column ->
// coalesced 256B), killing R9's 16-lane scatter without LDS staging.
// LDS 27.6KB -> 4 blocks/CU under (256,4). m_i never touches global.
// ---------------------------------------------------------------------------

typedef _Float16 f16;
typedef _Float16 h8 __attribute__((ext_vector_type(8)));
typedef float f4 __attribute__((ext_vector_type(4)));

#define MFMA16(a, b, c) __builtin_amdgcn_mfma_f32_16x16x32_f16(a, b, c, 0, 0, 0)
#define WFENCE()                        \
  do {                                  \
    __builtin_amdgcn_wave_barrier();    \
    __asm__ volatile("" ::: "memory");  \
  } while (0)

// ---- workspace byte offsets ----
#define H_OFF 0           // f32 [128][64][64]
#define Q_OFF 2097152     // f32 [128][64][64]  (b2a folded)
#define P_OFF 4194304     // f32 [128][64][64]
#define WQ_OFF 6291456
// within WQ:
#define O_W45B 0         // f32 w64[64], w65[64], b2a[64]
#define O_W2BTH 768      // f16 [32v][64k] hi of W2b[k][v]
#define O_W2BTL 4864     // f16 lo
#define O_B2B 8960       // f32 [32]
#define O_W2CTH 9088     // f16 [32v][32k] hi
#define O_W2CTL 11136    // f16 lo
#define O_B2C 13184      // f32 [32]

// ---- k_iter LDS (27648 B) ----
#define LI_M2W 0      // per-wave m2: 4 x 2560 (hi|lo), P2 only; overlays after:
#define LI_ND 0       //   f32 [8][32] node (tail)
#define LI_HN 1024    //   f32 [8][64] h_new (tail)
#define LI_T1 3072    //   f32 [8][68] readout t1 (last)
#define LI_T2 5248    //   f32 [8][36] readout t2 (last)
#define LI_W2BH 10240 // f16 [32v][72] (row-padded 64->72)
#define LI_W2BL 14848
#define LI_W2CH 19456 // f16 [32v][40] (row-padded 32->40)
#define LI_W2CL 22016
#define LI_MACC 24576 // f32 [8][32] m_i
#define LI_H32 25600  // f32 [8][64] h_old
#define LI_TOTAL 27648

__device__ __forceinline__ float fast_rcp(float x) {
#if __has_builtin(__builtin_amdgcn_rcpf)
  return __builtin_amdgcn_rcpf(x);
#else
  return 1.0f / x;
#endif
}
// jax.nn.gelu(approximate=True) — R5-exact formulation (absmax-16-verified)
__device__ __forceinline__ float gelu_f(float x) {
  float x3 = x * x * x;
  float u = -1.5957691216057308f * fmaf(0.044715f, x3, x);
  return x * fast_rcp(1.f + __expf(u));
}
__device__ __forceinline__ float sigm_f(float x) {
  return fast_rcp(1.f + __expf(-x));
}
__device__ __forceinline__ void splitw(float v, f16& h, f16& l) {
  h = (f16)v;
  l = (f16)(v - (float)h);
}

// ===========================================================================
__global__ __launch_bounds__(256) void k_pre(
    const float* __restrict__ node0, const float* __restrict__ W1,
    const float* __restrict__ b1, const float* __restrict__ W2a,
    const float* __restrict__ b2a, const float* __restrict__ W2b,
    const float* __restrict__ b2b, const float* __restrict__ W2c,
    const float* __restrict__ b2c, float* __restrict__ ws) {
  const int t = threadIdx.x;
  const int blk = blockIdx.x;
  char* wsb = (char*)ws;
  float* Qbuf = (float*)(wsb + Q_OFF);
  float* Pbuf = (float*)(wsb + P_OFF);
  char* W = wsb + WQ_OFF;

  if (blk < 256) {  // fc1a + iter-1 Q/P seed: 2 blocks/batch, 32 nodes
    __shared__ float sNode[1024];
    const int b = blk >> 1;
    const int n0 = (blk & 1) << 5;
    for (int idx = t; idx < 1024; idx += 256) {
      const int n = idx >> 5, f = idx & 31;
      float acc = b1[f];
#pragma unroll
      for (int k = 0; k < 8; ++k)
        acc = fmaf(node0[((size_t)(b * 64 + n0 + n)) * 8 + k], W1[k * 32 + f], acc);
      sNode[idx] = acc;
    }
    __syncthreads();
    // Q/P projection, coalesced: lane = u column; 16 nodes per thread
    const int u = t & 63;
    const int sel = (t >> 6) & 1;
    const int nb = t >> 7;  // 0 or 1; node n = nb + 2*o
    const float binit = sel ? 0.f : b2a[u];
    float acc[16];
#pragma unroll
    for (int o = 0; o < 16; ++o) acc[o] = binit;
    const float* wcol = W2a + (sel ? 2048 : 0) + u;
    for (int k = 0; k < 32; ++k) {
      const float w = wcol[k * 64];
#pragma unroll
      for (int o = 0; o < 16; ++o)
        acc[o] = fmaf(sNode[(nb + 2 * o) * 32 + k], w, acc[o]);
    }
    float* dst = sel ? Pbuf : Qbuf;
#pragma unroll
    for (int o = 0; o < 16; ++o)
      dst[((size_t)(b * 64 + n0 + nb + 2 * o)) * 64 + u] = acc[o];
  } else {  // weight prep for the edge MLP
    float* wb = (float*)(W + O_W45B);
    if (t < 64) {
      wb[t] = W2a[64 * 64 + t];
      wb[64 + t] = W2a[65 * 64 + t];
      wb[128 + t] = b2a[t];
    }
    f16* bth = (f16*)(W + O_W2BTH);
    f16* btl = (f16*)(W + O_W2BTL);
    for (int idx = t; idx < 2048; idx += 256) {
      const int k = idx >> 5, v = idx & 31;
      f16 h_, l_;
      splitw(W2b[k * 32 + v], h_, l_);
      bth[v * 64 + k] = h_;
      btl[v * 64 + k] = l_;
    }
    float* b2bf = (float*)(W + O_B2B);
    if (t < 32) b2bf[t] = b2b[t];
    f16* cth = (f16*)(W + O_W2CTH);
    f16* ctl = (f16*)(W + O_W2CTL);
    for (int idx = t; idx < 1024; idx += 256) {
      const int k = idx >> 5, v = idx & 31;
      f16 h_, l_;
      splitw(W2c[k * 32 + v], h_, l_);
      cth[v * 32 + k] = h_;
      ctl[v * 32 + k] = l_;
    }
    float* b2cf = (float*)(W + O_B2C);
    if (t < 32) b2cf[t] = b2c[t];
  }
}

// ===========================================================================
// Fused iteration: edge MLP (MFMA) + GRU + node update + Q/P | readout.
// Block = (batch, 8 source nodes); 1024 blocks.
__global__ __launch_bounds__(256, 4) void k_iter(
    const float* __restrict__ edge, float* __restrict__ ws,
    const float* __restrict__ h_in, const float* __restrict__ Wx,
    const float* __restrict__ Ux, const float* __restrict__ bx,
    const float* __restrict__ bh, const float* __restrict__ W3b,
    const float* __restrict__ b3b, const float* __restrict__ W2a,
    const float* __restrict__ b2a, const float* __restrict__ W4a,
    const float* __restrict__ b4a, const float* __restrict__ W4b,
    const float* __restrict__ b4b, const float* __restrict__ W4c,
    const float* __restrict__ b4c, float* __restrict__ out, const int is_last) {
  __shared__ alignas(16) char sm[LI_TOTAL];
  f16* sW2BH = (f16*)(sm + LI_W2BH);
  f16* sW2BL = (f16*)(sm + LI_W2BL);
  f16* sW2CH = (f16*)(sm + LI_W2CH);
  f16* sW2CL = (f16*)(sm + LI_W2CL);
  float* sMacc = (float*)(sm + LI_MACC);
  float* sH32 = (float*)(sm + LI_H32);

  const int tid = threadIdx.x;
  const int lane = tid & 63;
  const int wave = tid >> 6;
  const int col = lane & 15;
  const int quad = lane >> 4;
  const int b = blockIdx.x >> 3;
  const int i0 = (blockIdx.x & 7) << 3;

  char* wsb = (char*)ws;
  float* h_ws = (float*)(wsb + H_OFF);
  float* Qbuf = (float*)(wsb + Q_OFF);
  float* Pbuf = (float*)(wsb + P_OFF);
  const char* W = wsb + WQ_OFF;
  const float* w45b = (const float*)(W + O_W45B);
  const f16* W2BTHg = (const f16*)(W + O_W2BTH);
  const f16* W2BTLg = (const f16*)(W + O_W2BTL);
  const float* b2b_g = (const float*)(W + O_B2B);
  const f16* W2CTHg = (const f16*)(W + O_W2CTH);
  const f16* W2CTLg = (const f16*)(W + O_W2CTL);
  const float* b2c_g = (const float*)(W + O_B2C);

  // ---- stage: W2b/W2c splits to padded LDS; h rows ----
  for (int idx = tid; idx < 1024; idx += 256) {
    const int v = idx >> 5, k2 = idx & 31;
    ((unsigned int*)sW2BH)[v * 36 + k2] = ((const unsigned int*)W2BTHg)[idx];
    ((unsigned int*)sW2BL)[v * 36 + k2] = ((const unsigned int*)W2BTLg)[idx];
  }
  for (int idx = tid; idx < 512; idx += 256) {
    const int v = idx >> 4, k2 = idx & 15;
    ((unsigned int*)sW2CH)[v * 20 + k2] = ((const unsigned int*)W2CTHg)[idx];
    ((unsigned int*)sW2CL)[v * 20 + k2] = ((const unsigned int*)W2CTLg)[idx];
  }
  if (tid < 128) {
    const int nl = tid >> 4;
    const int k4 = (tid & 15) * 4;
    *(float4*)(sH32 + tid * 4) =
        *(const float4*)(h_in + ((size_t)(b * 64 + i0 + nl)) * 64 + k4);
  }
  __syncthreads();

  const float bb2[2] = {b2b_g[col], b2b_g[16 + col]};
  const float bc2[2] = {b2c_g[col], b2c_g[16 + col]};
  f4 wav[2][2], wbv[2][2];
#pragma unroll
  for (int kh = 0; kh < 2; ++kh) {
#pragma unroll
    for (int p = 0; p < 2; ++p) {
      wav[kh][p] = *(const f4*)(w45b + kh * 32 + quad * 8 + p * 4);
      wbv[kh][p] = *(const f4*)(w45b + 64 + kh * 32 + quad * 8 + p * 4);
    }
  }
  f16* m2h = (f16*)(sm + LI_M2W + wave * 2560);
  f16* m2l = m2h + 640;

  // ---- P2: edge MLP, wave-owned chunks (2/wave), R10-exact ----
#pragma unroll 1
  for (int cc2 = 0; cc2 < 2; ++cc2) {
    const int c = wave + 4 * cc2;
    const int ig = i0 + c;
    f4 qb[2][2];
#pragma unroll
    for (int kh = 0; kh < 2; ++kh)
#pragma unroll
      for (int p = 0; p < 2; ++p)
        qb[kh][p] = *(const f4*)(Qbuf + ((size_t)(b * 64 + ig)) * 64 + kh * 32 +
                                 quad * 8 + p * 4);
    const float* erow = edge + ((size_t)b * 4032 + (size_t)ig * 63) * 2;
    float ev0[4], ev1[4];
#pragma unroll
    for (int mt = 0; mt < 4; ++mt) {
      const int ko = mt * 16 + col;
      if (ko < 63) {
        const float2 e = *(const float2*)(erow + ko * 2);
        ev0[mt] = e.x;
        ev1[mt] = e.y;
      } else {
        ev0[mt] = 0.f;
        ev1[mt] = 0.f;
      }
    }
    float racc[2] = {0.f, 0.f};
#pragma unroll
    for (int mt = 0; mt < 4; ++mt) {
      const int ko = mt * 16 + col;
      int j = ko + ((ko >= ig) ? 1 : 0);
      j = (j > 63) ? 63 : j;
      const float e0 = ev0[mt], e1 = ev1[mt];
      h8 ah[2], al[2];
#pragma unroll
      for (int kh = 0; kh < 2; ++kh) {
        const float* prow =
            Pbuf + ((size_t)(b * 64 + j)) * 64 + kh * 32 + quad * 8;
        const f4 p0 = *(const f4*)prow;
        const f4 p1 = *(const f4*)(prow + 4);
#pragma unroll
        for (int jj = 0; jj < 4; ++jj) {
          float v = qb[kh][0][jj] + p0[jj];
          v = fmaf(e1, wbv[kh][0][jj], fmaf(e0, wav[kh][0][jj], v));
          float g = gelu_f(v) * 0.015625f;
          f16 hi = (f16)g;
          ah[kh][jj] = hi;
          al[kh][jj] = (f16)(g - (float)hi);
          v = qb[kh][1][jj] + p1[jj];
          v = fmaf(e1, wbv[kh][1][jj], fmaf(e0, wav[kh][1][jj], v));
          g = gelu_f(v) * 0.015625f;
          hi = (f16)g;
          ah[kh][4 + jj] = hi;
          al[kh][4 + jj] = (f16)(g - (float)hi);
        }
      }
#pragma unroll
      for (int nt = 0; nt < 2; ++nt) {
        const f16* rbh = sW2BH + (nt * 16 + col) * 72 + quad * 8;
        const f16* rbl = sW2BL + (nt * 16 + col) * 72 + quad * 8;
        const h8 bh0 = *(const h8*)rbh;
        const h8 bh1 = *(const h8*)(rbh + 32);
        const h8 bl0 = *(const h8*)rbl;
        const h8 bl1 = *(const h8*)(rbl + 32);
        f4 cm = {0.f, 0.f, 0.f, 0.f};
        cm = MFMA16(ah[0], bh0, cm);
        cm = MFMA16(ah[1], bh1, cm);
        cm = MFMA16(ah[0], bl0, cm);
        cm = MFMA16(ah[1], bl1, cm);
        cm = MFMA16(al[0], bh0, cm);
        cm = MFMA16(al[1], bh1, cm);
#pragma unroll
        for (int r = 0; r < 4; ++r) {
          const float g = gelu_f(fmaf(64.f, cm[r], bb2[nt])) * 0.015625f;
          const f16 hi = (f16)g;
          const int o = (quad * 4 + r) * 40 + nt * 16 + col;
          m2h[o] = hi;
          m2l[o] = (f16)(g - (float)hi);
        }
      }
      WFENCE();
      const h8 a2h = *(const h8*)(m2h + col * 40 + quad * 8);
      const h8 a2l = *(const h8*)(m2l + col * 40 + quad * 8);
      WFENCE();
#pragma unroll
      for (int nt = 0; nt < 2; ++nt) {
        const h8 bch = *(const h8*)(sW2CH + (nt * 16 + col) * 40 + quad * 8);
        const h8 bcl = *(const h8*)(sW2CL + (nt * 16 + col) * 40 + quad * 8);
        f4 dm = {0.f, 0.f, 0.f, 0.f};
        dm = MFMA16(a2h, bch, dm);
        dm = MFMA16(a2h, bcl, dm);
        dm = MFMA16(a2l, bch, dm);
#pragma unroll
        for (int r = 0; r < 4; ++r) {
          const int slot3 = mt * 16 + quad * 4 + r;
          const float g = gelu_f(fmaf(64.f, dm[r], bc2[nt]));
          racc[nt] += (slot3 != 63) ? g : 0.f;
        }
      }
    }
    racc[0] += __shfl_xor(racc[0], 16);
    racc[0] += __shfl_xor(racc[0], 32);
    racc[1] += __shfl_xor(racc[1], 16);
    racc[1] += __shfl_xor(racc[1], 32);
    if (lane < 32) sMacc[c * 32 + lane] = (lane < 16) ? racc[0] : racc[1];
  }
  __syncthreads();

  // ---- GRU tail: 2 nodes/thread, coalesced original-layout weights ----
  float* sHn = (float*)(sm + LI_HN);
  {
    const int u = lane;
    const int n0 = wave, n1 = wave + 4;
    float axr0 = 0.f, axz0 = 0.f, axn0 = 0.f;
    float axr1 = 0.f, axz1 = 0.f, axn1 = 0.f;
    for (int k = 0; k < 32; ++k) {
      const float w0 = Wx[k * 192 + u];
      const float w1 = Wx[k * 192 + 64 + u];
      const float w2 = Wx[k * 192 + 128 + u];
      const float m0 = sMacc[n0 * 32 + k];
      const float m1 = sMacc[n1 * 32 + k];
      axr0 = fmaf(m0, w0, axr0);
      axz0 = fmaf(m0, w1, axz0);
      axn0 = fmaf(m0, w2, axn0);
      axr1 = fmaf(m1, w0, axr1);
      axz1 = fmaf(m1, w1, axz1);
      axn1 = fmaf(m1, w2, axn1);
    }
    float ahr0 = 0.f, ahz0 = 0.f, ahn0 = 0.f;
    float ahr1 = 0.f, ahz1 = 0.f, ahn1 = 0.f;
    for (int k = 0; k < 64; ++k) {
      const float w0 = Ux[k * 192 + u];
      const float w1 = Ux[k * 192 + 64 + u];
      const float w2 = Ux[k * 192 + 128 + u];
      const float h0 = sH32[n0 * 64 + k];
      const float h1 = sH32[n1 * 64 + k];
      ahr0 = fmaf(h0, w0, ahr0);
      ahz0 = fmaf(h0, w1, ahz0);
      ahn0 = fmaf(h0, w2, ahn0);
      ahr1 = fmaf(h1, w0, ahr1);
      ahz1 = fmaf(h1, w1, ahz1);
      ahn1 = fmaf(h1, w2, ahn1);
    }
    const float bxr = bx[u], bhr = bh[u];
    const float bxz = bx[64 + u], bhz = bh[64 + u];
    const float bxn = bx[128 + u], bhn = bh[128 + u];
    {
      const float r_ = sigm_f(axr0 + ahr0 + bxr + bhr);
      const float z_ = sigm_f(axz0 + ahz0 + bxz + bhz);
      const float n_ = gelu_f(fmaf(r_, ahn0 + bhn, axn0 + bxn));
      const float hold = sH32[n0 * 64 + u];
      const float hnew = (1.f - z_) * n_ + z_ * hold;
      sHn[n0 * 64 + u] = hnew;
      if (!is_last) h_ws[((size_t)(b * 64 + i0 + n0)) * 64 + u] = hnew;
    }
    {
      const float r_ = sigm_f(axr1 + ahr1 + bxr + bhr);
      const float z_ = sigm_f(axz1 + ahz1 + bxz + bhz);
      const float n_ = gelu_f(fmaf(r_, ahn1 + bhn, axn1 + bxn));
      const float hold = sH32[n1 * 64 + u];
      const float hnew = (1.f - z_) * n_ + z_ * hold;
      sHn[n1 * 64 + u] = hnew;
      if (!is_last) h_ws[((size_t)(b * 64 + i0 + n1)) * 64 + u] = hnew;
    }
  }
  __syncthreads();

  // ---- node = h_new @ W3b + b3b ----
  float* sNd = (float*)(sm + LI_ND);
  {
    const int nn = tid >> 5, f = tid & 31;
    float acc = b3b[f];
    for (int k = 0; k < 64; ++k)
      acc = fmaf(sHn[nn * 64 + k], W3b[k * 32 + f], acc);
    sNd[nn * 32 + f] = acc;
  }
  __syncthreads();

  if (!is_last) {
    // ---- next-iter Q/P projection: 4 nodes/thread, coalesced W2a ----
    const int u = lane;
    const int sel = (tid >> 6) & 1;
    const int nb = tid >> 7;
    const float binit = sel ? 0.f : b2a[u];
    float acc[4] = {binit, binit, binit, binit};
    const float* wcol = W2a + (sel ? 2048 : 0) + u;
    for (int k = 0; k < 32; ++k) {
      const float w = wcol[k * 64];
      acc[0] = fmaf(sNd[(nb + 0) * 32 + k], w, acc[0]);
      acc[1] = fmaf(sNd[(nb + 2) * 32 + k], w, acc[1]);
      acc[2] = fmaf(sNd[(nb + 4) * 32 + k], w, acc[2]);
      acc[3] = fmaf(sNd[(nb + 6) * 32 + k], w, acc[3]);
    }
    float* dst = sel ? Pbuf : Qbuf;
#pragma unroll
    for (int o = 0; o < 4; ++o)
      dst[((size_t)(b * 64 + i0 + nb + 2 * o)) * 64 + u] = acc[o];
  } else {
    // ---- readout ----
    float* sT1 = (float*)(sm + LI_T1);
    float* sT2 = (float*)(sm + LI_T2);
    {
      const int u = lane;
      float acc0 = b4a[u], acc1 = b4a[u];
      for (int k = 0; k < 32; ++k) {
        const float w = W4a[k * 64 + u];
        acc0 = fmaf(sNd[wave * 32 + k], w, acc0);
        acc1 = fmaf(sNd[(wave + 4) * 32 + k], w, acc1);
      }
      sT1[wave * 68 + u] = acc0;
      sT1[(wave + 4) * 68 + u] = acc1;
    }
    __syncthreads();
    {
      const int nn = tid >> 5, v = tid & 31;
      float acc = b4b[v];
      for (int k = 0; k < 64; ++k)
        acc = fmaf(sT1[nn * 68 + k], W4b[k * 32 + v], acc);
      sT2[nn * 36 + v] = acc;
    }
    __syncthreads();
    {
      const int nn = tid >> 5, f = tid & 31;
      float acc = b4c[f];
      for (int k = 0; k < 32; ++k)
        acc = fmaf(sT2[nn * 36 + k], W4c[k * 32 + f], acc);
      out[((size_t)(b * 64 + i0 + nn)) * 32 + f] = acc;
    }
  }
}

// ===========================================================================
extern "C" void kernel_launch(void* const* d_in, const int* in_sizes, int n_in,
                              void* d_out, int out_size, void* d_ws, size_t ws_size,
                              hipStream_t stream) {
  (void)in_sizes;
  (void)n_in;
  (void)out_size;
  (void)ws_size;
  const float* node0 = (const float*)d_in[0];
  const float* edge = (const float*)d_in[1];
  const float* hin = (const float*)d_in[4];
  const float* W1 = (const float*)d_in[5];
  const float* b1 = (const float*)d_in[6];
  const float* W2a = (const float*)d_in[7];
  const float* b2a = (const float*)d_in[8];
  const float* W2b = (const float*)d_in[9];
  const float* b2b = (const float*)d_in[10];
  const float* W2c = (const float*)d_in[11];
  const float* b2c = (const float*)d_in[12];
  const float* Wx = (const float*)d_in[13];
  const float* Ux = (const float*)d_in[14];
  const float* bx = (const float*)d_in[15];
  const float* bh = (const float*)d_in[16];
  const float* W3b = (const float*)d_in[17];
  const float* b3b = (const float*)d_in[18];
  const float* W4a = (const float*)d_in[19];
  const float* b4a = (const float*)d_in[20];
  const float* W4b = (const float*)d_in[21];
  const float* b4b = (const float*)d_in[22];
  const float* W4c = (const float*)d_in[23];
  const float* b4c = (const float*)d_in[24];

  float* ws = (float*)d_ws;
  char* wsb = (char*)d_ws;
  float* h_ws = (float*)(wsb + H_OFF);
  float* out = (float*)d_out;

  k_pre<<<dim3(257), dim3(256), 0, stream>>>(node0, W1, b1, W2a, b2a, W2b, b2b, W2c,
                                             b2c, ws);
  k_iter<<<dim3(1024), dim3(256), 0, stream>>>(edge, ws, hin, Wx, Ux, bx, bh, W3b,
                                               b3b, W2a, b2a, W4a, b4a, W4b, b4b,
                                               W4c, b4c, nullptr, 0);
  k_iter<<<dim3(1024), dim3(256), 0, stream>>>(edge, ws, h_ws, Wx, Ux, bx, bh, W3b,
                                               b3b, W2a, b2a, W4a, b4a, W4b, b4b,
                                               W4c, b4c, nullptr, 0);
  k_iter<<<dim3(1024), dim3(256), 0, stream>>>(edge, ws, h_ws, Wx, Ux, bx, bh, W3b,
                                               b3b, W2a, b2a, W4a, b4a, W4b, b4b,
                                               W4c, b4c, out, 1);
}

// Round 12
// 281.127 us; speedup vs baseline: 1.4668x; 1.4668x over previous
//
#include <hip/hip_runtime.h>

// ---------------------------------------------------------------------------
// GNN forward, MI355X. All I/O f32; split-f16 MFMA edge MLP (R8-verified,
// bit-identical); GRU/projections f32 VALU, bit-identical per-output order.
// R12 = R11 fused structure + spill surgery. R11 evidence: WRITE 116MB /
// FETCH 65MB / HBM 1.5TB/s under (256,4) -> the fused GRU tail (12 live
// accumulators + fully-unrolled 3-stream weight loops) blew the 128-total
// unified VGPR budget. Fix: GRU processes its 2 nodes sequentially (6 accs)
// with clamped unrolling (~12 loads in flight); tail k-loops unroll-limited.
// Per-output FMA order unchanged everywhere -> absmax stays 16.
// LDS 27.6KB, 4 blocks/CU, occupancy ~44% (proven by R11's counter).
// ---------------------------------------------------------------------------

typedef _Float16 f16;
typedef _Float16 h8 __attribute__((ext_vector_type(8)));
typedef float f4 __attribute__((ext_vector_type(4)));

#define MFMA16(a, b, c) __builtin_amdgcn_mfma_f32_16x16x32_f16(a, b, c, 0, 0, 0)
#define WFENCE()                        \
  do {                                  \
    __builtin_amdgcn_wave_barrier();    \
    __asm__ volatile("" ::: "memory");  \
  } while (0)

// ---- workspace byte offsets ----
#define H_OFF 0           // f32 [128][64][64]
#define Q_OFF 2097152     // f32 [128][64][64]  (b2a folded)
#define P_OFF 4194304     // f32 [128][64][64]
#define WQ_OFF 6291456
// within WQ:
#define O_W45B 0         // f32 w64[64], w65[64], b2a[64]
#define O_W2BTH 768      // f16 [32v][64k] hi of W2b[k][v]
#define O_W2BTL 4864     // f16 lo
#define O_B2B 8960       // f32 [32]
#define O_W2CTH 9088     // f16 [32v][32k] hi
#define O_W2CTL 11136    // f16 lo
#define O_B2C 13184      // f32 [32]

// ---- k_iter LDS (27648 B) ----
#define LI_M2W 0      // per-wave m2: 4 x 2560 (hi|lo), P2 only; overlays after:
#define LI_ND 0       //   f32 [8][32] node (tail)
#define LI_HN 1024    //   f32 [8][64] h_new (tail)
#define LI_T1 3072    //   f32 [8][68] readout t1 (last)
#define LI_T2 5248    //   f32 [8][36] readout t2 (last)
#define LI_W2BH 10240 // f16 [32v][72] (row-padded 64->72)
#define LI_W2BL 14848
#define LI_W2CH 19456 // f16 [32v][40] (row-padded 32->40)
#define LI_W2CL 22016
#define LI_MACC 24576 // f32 [8][32] m_i
#define LI_H32 25600  // f32 [8][64] h_old
#define LI_TOTAL 27648

__device__ __forceinline__ float fast_rcp(float x) {
#if __has_builtin(__builtin_amdgcn_rcpf)
  return __builtin_amdgcn_rcpf(x);
#else
  return 1.0f / x;
#endif
}
// jax.nn.gelu(approximate=True) — R5-exact formulation (absmax-16-verified)
__device__ __forceinline__ float gelu_f(float x) {
  float x3 = x * x * x;
  float u = -1.5957691216057308f * fmaf(0.044715f, x3, x);
  return x * fast_rcp(1.f + __expf(u));
}
__device__ __forceinline__ float sigm_f(float x) {
  return fast_rcp(1.f + __expf(-x));
}
__device__ __forceinline__ void splitw(float v, f16& h, f16& l) {
  h = (f16)v;
  l = (f16)(v - (float)h);
}

// ===========================================================================
__global__ __launch_bounds__(256) void k_pre(
    const float* __restrict__ node0, const float* __restrict__ W1,
    const float* __restrict__ b1, const float* __restrict__ W2a,
    const float* __restrict__ b2a, const float* __restrict__ W2b,
    const float* __restrict__ b2b, const float* __restrict__ W2c,
    const float* __restrict__ b2c, float* __restrict__ ws) {
  const int t = threadIdx.x;
  const int blk = blockIdx.x;
  char* wsb = (char*)ws;
  float* Qbuf = (float*)(wsb + Q_OFF);
  float* Pbuf = (float*)(wsb + P_OFF);
  char* W = wsb + WQ_OFF;

  if (blk < 256) {  // fc1a + iter-1 Q/P seed: 2 blocks/batch, 32 nodes
    __shared__ float sNode[1024];
    const int b = blk >> 1;
    const int n0 = (blk & 1) << 5;
    for (int idx = t; idx < 1024; idx += 256) {
      const int n = idx >> 5, f = idx & 31;
      float acc = b1[f];
#pragma unroll
      for (int k = 0; k < 8; ++k)
        acc = fmaf(node0[((size_t)(b * 64 + n0 + n)) * 8 + k], W1[k * 32 + f], acc);
      sNode[idx] = acc;
    }
    __syncthreads();
    // Q/P projection, coalesced: lane = u column; 16 nodes per thread
    const int u = t & 63;
    const int sel = (t >> 6) & 1;
    const int nb = t >> 7;  // 0 or 1; node n = nb + 2*o
    const float binit = sel ? 0.f : b2a[u];
    float acc[16];
#pragma unroll
    for (int o = 0; o < 16; ++o) acc[o] = binit;
    const float* wcol = W2a + (sel ? 2048 : 0) + u;
#pragma unroll 4
    for (int k = 0; k < 32; ++k) {
      const float w = wcol[k * 64];
#pragma unroll
      for (int o = 0; o < 16; ++o)
        acc[o] = fmaf(sNode[(nb + 2 * o) * 32 + k], w, acc[o]);
    }
    float* dst = sel ? Pbuf : Qbuf;
#pragma unroll
    for (int o = 0; o < 16; ++o)
      dst[((size_t)(b * 64 + n0 + nb + 2 * o)) * 64 + u] = acc[o];
  } else {  // weight prep for the edge MLP
    float* wb = (float*)(W + O_W45B);
    if (t < 64) {
      wb[t] = W2a[64 * 64 + t];
      wb[64 + t] = W2a[65 * 64 + t];
      wb[128 + t] = b2a[t];
    }
    f16* bth = (f16*)(W + O_W2BTH);
    f16* btl = (f16*)(W + O_W2BTL);
    for (int idx = t; idx < 2048; idx += 256) {
      const int k = idx >> 5, v = idx & 31;
      f16 h_, l_;
      splitw(W2b[k * 32 + v], h_, l_);
      bth[v * 64 + k] = h_;
      btl[v * 64 + k] = l_;
    }
    float* b2bf = (float*)(W + O_B2B);
    if (t < 32) b2bf[t] = b2b[t];
    f16* cth = (f16*)(W + O_W2CTH);
    f16* ctl = (f16*)(W + O_W2CTL);
    for (int idx = t; idx < 1024; idx += 256) {
      const int k = idx >> 5, v = idx & 31;
      f16 h_, l_;
      splitw(W2c[k * 32 + v], h_, l_);
      cth[v * 32 + k] = h_;
      ctl[v * 32 + k] = l_;
    }
    float* b2cf = (float*)(W + O_B2C);
    if (t < 32) b2cf[t] = b2c[t];
  }
}

// ===========================================================================
// Fused iteration: edge MLP (MFMA) + GRU + node update + Q/P | readout.
// Block = (batch, 8 source nodes); 1024 blocks.
__global__ __launch_bounds__(256, 4) void k_iter(
    const float* __restrict__ edge, float* __restrict__ ws,
    const float* __restrict__ h_in, const float* __restrict__ Wx,
    const float* __restrict__ Ux, const float* __restrict__ bx,
    const float* __restrict__ bh, const float* __restrict__ W3b,
    const float* __restrict__ b3b, const float* __restrict__ W2a,
    const float* __restrict__ b2a, const float* __restrict__ W4a,
    const float* __restrict__ b4a, const float* __restrict__ W4b,
    const float* __restrict__ b4b, const float* __restrict__ W4c,
    const float* __restrict__ b4c, float* __restrict__ out, const int is_last) {
  __shared__ alignas(16) char sm[LI_TOTAL];
  f16* sW2BH = (f16*)(sm + LI_W2BH);
  f16* sW2BL = (f16*)(sm + LI_W2BL);
  f16* sW2CH = (f16*)(sm + LI_W2CH);
  f16* sW2CL = (f16*)(sm + LI_W2CL);
  float* sMacc = (float*)(sm + LI_MACC);
  float* sH32 = (float*)(sm + LI_H32);

  const int tid = threadIdx.x;
  const int lane = tid & 63;
  const int wave = tid >> 6;
  const int col = lane & 15;
  const int quad = lane >> 4;
  const int b = blockIdx.x >> 3;
  const int i0 = (blockIdx.x & 7) << 3;

  char* wsb = (char*)ws;
  float* h_ws = (float*)(wsb + H_OFF);
  float* Qbuf = (float*)(wsb + Q_OFF);
  float* Pbuf = (float*)(wsb + P_OFF);
  const char* W = wsb + WQ_OFF;
  const float* w45b = (const float*)(W + O_W45B);
  const f16* W2BTHg = (const f16*)(W + O_W2BTH);
  const f16* W2BTLg = (const f16*)(W + O_W2BTL);
  const float* b2b_g = (const float*)(W + O_B2B);
  const f16* W2CTHg = (const f16*)(W + O_W2CTH);
  const f16* W2CTLg = (const f16*)(W + O_W2CTL);
  const float* b2c_g = (const float*)(W + O_B2C);

  // ---- stage: W2b/W2c splits to padded LDS; h rows ----
  for (int idx = tid; idx < 1024; idx += 256) {
    const int v = idx >> 5, k2 = idx & 31;
    ((unsigned int*)sW2BH)[v * 36 + k2] = ((const unsigned int*)W2BTHg)[idx];
    ((unsigned int*)sW2BL)[v * 36 + k2] = ((const unsigned int*)W2BTLg)[idx];
  }
  for (int idx = tid; idx < 512; idx += 256) {
    const int v = idx >> 4, k2 = idx & 15;
    ((unsigned int*)sW2CH)[v * 20 + k2] = ((const unsigned int*)W2CTHg)[idx];
    ((unsigned int*)sW2CL)[v * 20 + k2] = ((const unsigned int*)W2CTLg)[idx];
  }
  if (tid < 128) {
    const int nl = tid >> 4;
    const int k4 = (tid & 15) * 4;
    *(float4*)(sH32 + tid * 4) =
        *(const float4*)(h_in + ((size_t)(b * 64 + i0 + nl)) * 64 + k4);
  }
  __syncthreads();

  const float bb2[2] = {b2b_g[col], b2b_g[16 + col]};
  const float bc2[2] = {b2c_g[col], b2c_g[16 + col]};
  f4 wav[2][2], wbv[2][2];
#pragma unroll
  for (int kh = 0; kh < 2; ++kh) {
#pragma unroll
    for (int p = 0; p < 2; ++p) {
      wav[kh][p] = *(const f4*)(w45b + kh * 32 + quad * 8 + p * 4);
      wbv[kh][p] = *(const f4*)(w45b + 64 + kh * 32 + quad * 8 + p * 4);
    }
  }
  f16* m2h = (f16*)(sm + LI_M2W + wave * 2560);
  f16* m2l = m2h + 640;

  // ---- P2: edge MLP, wave-owned chunks (2/wave), R10-exact ----
#pragma unroll 1
  for (int cc2 = 0; cc2 < 2; ++cc2) {
    const int c = wave + 4 * cc2;
    const int ig = i0 + c;
    f4 qb[2][2];
#pragma unroll
    for (int kh = 0; kh < 2; ++kh)
#pragma unroll
      for (int p = 0; p < 2; ++p)
        qb[kh][p] = *(const f4*)(Qbuf + ((size_t)(b * 64 + ig)) * 64 + kh * 32 +
                                 quad * 8 + p * 4);
    const float* erow = edge + ((size_t)b * 4032 + (size_t)ig * 63) * 2;
    float ev0[4], ev1[4];
#pragma unroll
    for (int mt = 0; mt < 4; ++mt) {
      const int ko = mt * 16 + col;
      if (ko < 63) {
        const float2 e = *(const float2*)(erow + ko * 2);
        ev0[mt] = e.x;
        ev1[mt] = e.y;
      } else {
        ev0[mt] = 0.f;
        ev1[mt] = 0.f;
      }
    }
    float racc[2] = {0.f, 0.f};
#pragma unroll
    for (int mt = 0; mt < 4; ++mt) {
      const int ko = mt * 16 + col;
      int j = ko + ((ko >= ig) ? 1 : 0);
      j = (j > 63) ? 63 : j;
      const float e0 = ev0[mt], e1 = ev1[mt];
      h8 ah[2], al[2];
#pragma unroll
      for (int kh = 0; kh < 2; ++kh) {
        const float* prow =
            Pbuf + ((size_t)(b * 64 + j)) * 64 + kh * 32 + quad * 8;
        const f4 p0 = *(const f4*)prow;
        const f4 p1 = *(const f4*)(prow + 4);
#pragma unroll
        for (int jj = 0; jj < 4; ++jj) {
          float v = qb[kh][0][jj] + p0[jj];
          v = fmaf(e1, wbv[kh][0][jj], fmaf(e0, wav[kh][0][jj], v));
          float g = gelu_f(v) * 0.015625f;
          f16 hi = (f16)g;
          ah[kh][jj] = hi;
          al[kh][jj] = (f16)(g - (float)hi);
          v = qb[kh][1][jj] + p1[jj];
          v = fmaf(e1, wbv[kh][1][jj], fmaf(e0, wav[kh][1][jj], v));
          g = gelu_f(v) * 0.015625f;
          hi = (f16)g;
          ah[kh][4 + jj] = hi;
          al[kh][4 + jj] = (f16)(g - (float)hi);
        }
      }
#pragma unroll
      for (int nt = 0; nt < 2; ++nt) {
        const f16* rbh = sW2BH + (nt * 16 + col) * 72 + quad * 8;
        const f16* rbl = sW2BL + (nt * 16 + col) * 72 + quad * 8;
        const h8 bh0 = *(const h8*)rbh;
        const h8 bh1 = *(const h8*)(rbh + 32);
        const h8 bl0 = *(const h8*)rbl;
        const h8 bl1 = *(const h8*)(rbl + 32);
        f4 cm = {0.f, 0.f, 0.f, 0.f};
        cm = MFMA16(ah[0], bh0, cm);
        cm = MFMA16(ah[1], bh1, cm);
        cm = MFMA16(ah[0], bl0, cm);
        cm = MFMA16(ah[1], bl1, cm);
        cm = MFMA16(al[0], bh0, cm);
        cm = MFMA16(al[1], bh1, cm);
#pragma unroll
        for (int r = 0; r < 4; ++r) {
          const float g = gelu_f(fmaf(64.f, cm[r], bb2[nt])) * 0.015625f;
          const f16 hi = (f16)g;
          const int o = (quad * 4 + r) * 40 + nt * 16 + col;
          m2h[o] = hi;
          m2l[o] = (f16)(g - (float)hi);
        }
      }
      WFENCE();
      const h8 a2h = *(const h8*)(m2h + col * 40 + quad * 8);
      const h8 a2l = *(const h8*)(m2l + col * 40 + quad * 8);
      WFENCE();
#pragma unroll
      for (int nt = 0; nt < 2; ++nt) {
        const h8 bch = *(const h8*)(sW2CH + (nt * 16 + col) * 40 + quad * 8);
        const h8 bcl = *(const h8*)(sW2CL + (nt * 16 + col) * 40 + quad * 8);
        f4 dm = {0.f, 0.f, 0.f, 0.f};
        dm = MFMA16(a2h, bch, dm);
        dm = MFMA16(a2h, bcl, dm);
        dm = MFMA16(a2l, bch, dm);
#pragma unroll
        for (int r = 0; r < 4; ++r) {
          const int slot3 = mt * 16 + quad * 4 + r;
          const float g = gelu_f(fmaf(64.f, dm[r], bc2[nt]));
          racc[nt] += (slot3 != 63) ? g : 0.f;
        }
      }
    }
    racc[0] += __shfl_xor(racc[0], 16);
    racc[0] += __shfl_xor(racc[0], 32);
    racc[1] += __shfl_xor(racc[1], 16);
    racc[1] += __shfl_xor(racc[1], 32);
    if (lane < 32) sMacc[c * 32 + lane] = (lane < 16) ? racc[0] : racc[1];
  }
  __syncthreads();

  // ---- GRU tail: 1 node at a time (6 accs), clamped unroll, coalesced ----
  float* sHn = (float*)(sm + LI_HN);
  {
    const int u = lane;
    const float bxr = bx[u], bhr = bh[u];
    const float bxz = bx[64 + u], bhz = bh[64 + u];
    const float bxn = bx[128 + u], bhn = bh[128 + u];
#pragma unroll 1
    for (int p = 0; p < 2; ++p) {
      const int n0 = wave + 4 * p;
      float axr = 0.f, axz = 0.f, axn = 0.f;
#pragma unroll 4
      for (int k = 0; k < 32; ++k) {
        const float m0 = sMacc[n0 * 32 + k];
        axr = fmaf(m0, Wx[k * 192 + u], axr);
        axz = fmaf(m0, Wx[k * 192 + 64 + u], axz);
        axn = fmaf(m0, Wx[k * 192 + 128 + u], axn);
      }
      float ahr = 0.f, ahz = 0.f, ahn = 0.f;
#pragma unroll 4
      for (int k = 0; k < 64; ++k) {
        const float h0 = sH32[n0 * 64 + k];
        ahr = fmaf(h0, Ux[k * 192 + u], ahr);
        ahz = fmaf(h0, Ux[k * 192 + 64 + u], ahz);
        ahn = fmaf(h0, Ux[k * 192 + 128 + u], ahn);
      }
      const float r_ = sigm_f(axr + ahr + bxr + bhr);
      const float z_ = sigm_f(axz + ahz + bxz + bhz);
      const float n_ = gelu_f(fmaf(r_, ahn + bhn, axn + bxn));
      const float hold = sH32[n0 * 64 + u];
      const float hnew = (1.f - z_) * n_ + z_ * hold;
      sHn[n0 * 64 + u] = hnew;
      if (!is_last) h_ws[((size_t)(b * 64 + i0 + n0)) * 64 + u] = hnew;
    }
  }
  __syncthreads();

  // ---- node = h_new @ W3b + b3b ----
  float* sNd = (float*)(sm + LI_ND);
  {
    const int nn = tid >> 5, f = tid & 31;
    float acc = b3b[f];
#pragma unroll 8
    for (int k = 0; k < 64; ++k)
      acc = fmaf(sHn[nn * 64 + k], W3b[k * 32 + f], acc);
    sNd[nn * 32 + f] = acc;
  }
  __syncthreads();

  if (!is_last) {
    // ---- next-iter Q/P projection: 4 nodes/thread, coalesced W2a ----
    const int u = lane;
    const int sel = (tid >> 6) & 1;
    const int nb = tid >> 7;
    const float binit = sel ? 0.f : b2a[u];
    float acc[4] = {binit, binit, binit, binit};
    const float* wcol = W2a + (sel ? 2048 : 0) + u;
#pragma unroll 4
    for (int k = 0; k < 32; ++k) {
      const float w = wcol[k * 64];
      acc[0] = fmaf(sNd[(nb + 0) * 32 + k], w, acc[0]);
      acc[1] = fmaf(sNd[(nb + 2) * 32 + k], w, acc[1]);
      acc[2] = fmaf(sNd[(nb + 4) * 32 + k], w, acc[2]);
      acc[3] = fmaf(sNd[(nb + 6) * 32 + k], w, acc[3]);
    }
    float* dst = sel ? Pbuf : Qbuf;
#pragma unroll
    for (int o = 0; o < 4; ++o)
      dst[((size_t)(b * 64 + i0 + nb + 2 * o)) * 64 + u] = acc[o];
  } else {
    // ---- readout ----
    float* sT1 = (float*)(sm + LI_T1);
    float* sT2 = (float*)(sm + LI_T2);
    {
      const int u = lane;
      float acc0 = b4a[u], acc1 = b4a[u];
#pragma unroll 4
      for (int k = 0; k < 32; ++k) {
        const float w = W4a[k * 64 + u];
        acc0 = fmaf(sNd[wave * 32 + k], w, acc0);
        acc1 = fmaf(sNd[(wave + 4) * 32 + k], w, acc1);
      }
      sT1[wave * 68 + u] = acc0;
      sT1[(wave + 4) * 68 + u] = acc1;
    }
    __syncthreads();
    {
      const int nn = tid >> 5, v = tid & 31;
      float acc = b4b[v];
#pragma unroll 8
      for (int k = 0; k < 64; ++k)
        acc = fmaf(sT1[nn * 68 + k], W4b[k * 32 + v], acc);
      sT2[nn * 36 + v] = acc;
    }
    __syncthreads();
    {
      const int nn = tid >> 5, f = tid & 31;
      float acc = b4c[f];
#pragma unroll 8
      for (int k = 0; k < 32; ++k)
        acc = fmaf(sT2[nn * 36 + k], W4c[k * 32 + f], acc);
      out[((size_t)(b * 64 + i0 + nn)) * 32 + f] = acc;
    }
  }
}

// ===========================================================================
extern "C" void kernel_launch(void* const* d_in, const int* in_sizes, int n_in,
                              void* d_out, int out_size, void* d_ws, size_t ws_size,
                              hipStream_t stream) {
  (void)in_sizes;
  (void)n_in;
  (void)out_size;
  (void)ws_size;
  const float* node0 = (const float*)d_in[0];
  const float* edge = (const float*)d_in[1];
  const float* hin = (const float*)d_in[4];
  const float* W1 = (const float*)d_in[5];
  const float* b1 = (const float*)d_in[6];
  const float* W2a = (const float*)d_in[7];
  const float* b2a = (const float*)d_in[8];
  const float* W2b = (const float*)d_in[9];
  const float* b2b = (const float*)d_in[10];
  const float* W2c = (const float*)d_in[11];
  const float* b2c = (const float*)d_in[12];
  const float* Wx = (const float*)d_in[13];
  const float* Ux = (const float*)d_in[14];
  const float* bx = (const float*)d_in[15];
  const float* bh = (const float*)d_in[16];
  const float* W3b = (const float*)d_in[17];
  const float* b3b = (const float*)d_in[18];
  const float* W4a = (const float*)d_in[19];
  const float* b4a = (const float*)d_in[20];
  const float* W4b = (const float*)d_in[21];
  const float* b4b = (const float*)d_in[22];
  const float* W4c = (const float*)d_in[23];
  const float* b4c = (const float*)d_in[24];

  float* ws = (float*)d_ws;
  char* wsb = (char*)d_ws;
  float* h_ws = (float*)(wsb + H_OFF);
  float* out = (float*)d_out;

  k_pre<<<dim3(257), dim3(256), 0, stream>>>(node0, W1, b1, W2a, b2a, W2b, b2b, W2c,
                                             b2c, ws);
  k_iter<<<dim3(1024), dim3(256), 0, stream>>>(edge, ws, hin, Wx, Ux, bx, bh, W3b,
                                               b3b, W2a, b2a, W4a, b4a, W4b, b4b,
                                               W4c, b4c, nullptr, 0);
  k_iter<<<dim3(1024), dim3(256), 0, stream>>>(edge, ws, h_ws, Wx, Ux, bx, bh, W3b,
                                               b3b, W2a, b2a, W4a, b4a, W4b, b4b,
                                               W4c, b4c, nullptr, 0);
  k_iter<<<dim3(1024), dim3(256), 0, stream>>>(edge, ws, h_ws, Wx, Ux, bx, bh, W3b,
                                               b3b, W2a, b2a, W4a, b4a, W4b, b4b,
                                               W4c, b4c, out, 1);
}